// Round 10
// baseline (914.144 us; speedup 1.0000x reference)
//
#include <hip/hip_runtime.h>

#define NN 100000
#define NSTEP 5
#define LSTR 264   // ushorts; 528B rows, 16B aligned for ds_read_b128

typedef unsigned short ushort_t;
typedef __attribute__((ext_vector_type(8))) short short8;
typedef __attribute__((ext_vector_type(4))) float floatx4;

__device__ __forceinline__ ushort_t f2bf(float f){
  union { float f; unsigned u; } v; v.f = f;
  unsigned r = v.u + 0x7fffu + ((v.u >> 16) & 1u);
  return (ushort_t)(r >> 16);
}
__device__ __forceinline__ float bf2f(ushort_t s){
  union { unsigned u; float f; } v; v.u = ((unsigned)s) << 16;
  return v.f;
}
__device__ __forceinline__ float sigf(float x){ return 1.0f/(1.0f+__expf(-x)); }

// ================= fused FNN: hfeat = (elu(x@W1+b1))@W2+b2, bf16 out =================
// R7-exact (measured best: 75.4us, occ 55%). 3125 blocks x 512 thr, 32 rows x 256 cols.
// Weight pipelining via global_load_lds + counted vmcnt; per-wave private depth-2 ring, no
// barriers in the pipeline. R8's weights-in-registers regressed (allocator rematerializes
// at 108 VGPR; occ 18%; 84us) — registers are a dead end on this kernel, LDS rings are not.
__global__ __launch_bounds__(512) void fnn_fused(const float* __restrict__ x,
    const ushort_t* __restrict__ W1P, const float* __restrict__ b1,
    const ushort_t* __restrict__ W2P, const float* __restrict__ b2,
    ushort_t* __restrict__ hfeat, int M)
{
  __shared__ ushort_t buf[32 * LSTR];
  __shared__ ushort_t wst[2][8][2][512];   // [phase][wave][j][1KB chunk]
  int tid = threadIdx.x;
  int w = tid >> 6, lane = tid & 63, qd = lane >> 4, r16 = lane & 15;
  size_t row0 = (size_t)blockIdx.x * 32;

  typedef __attribute__((address_space(3))) unsigned int lds_u32;
  typedef __attribute__((address_space(1))) const unsigned int glb_u32;

  // hoisted biases (complete at the staging barrier -> vmcnt slate clean for the pipeline)
  float bb1[2], bb2[2];
  #pragma unroll
  for (int j = 0; j < 2; j++){
    int col = w*32 + j*16 + r16;
    bb1[j] = b1[col];
    bb2[j] = b2[col];
  }

  // ---- stage x tile (32x256 fp32 -> bf16 LDS) ----
  {
    float4 xv[4];
    #pragma unroll
    for (int it = 0; it < 4; it++){
      int idx = it * 512 + tid;
      xv[it] = *(const float4*)(x + (row0 + (idx >> 6)) * 256 + (idx & 63) * 4);
    }
    #pragma unroll
    for (int it = 0; it < 4; it++){
      int idx = it * 512 + tid;
      ushort4 pk = make_ushort4(f2bf(xv[it].x), f2bf(xv[it].y), f2bf(xv[it].z), f2bf(xv[it].w));
      *(ushort4*)&buf[(idx >> 6) * LSTR + (idx & 63) * 4] = pk;
    }
  }
  __syncthreads();   // x-tile visible; all prior vmem drained (clean FIFO)

  auto STAGE = [&](const ushort_t* __restrict__ P, int kc, int ph){
    #pragma unroll
    for (int j = 0; j < 2; j++){
      const ushort_t* gp = P + (size_t)(((w*2 + j)*8 + kc)*512) + lane*8;
      __builtin_amdgcn_global_load_lds((glb_u32*)gp, (lds_u32*)&wst[ph][w][j][0], 16, 0, 0);
    }
  };

  floatx4 acc[2][2];

  auto GEMM = [&](const ushort_t* __restrict__ P, bool prestaged){
    if (!prestaged){ STAGE(P, 0, 0); STAGE(P, 1, 1); }
    #pragma unroll
    for (int i=0;i<2;i++)
      #pragma unroll
      for (int j=0;j<2;j++) acc[i][j] = (floatx4){0.f,0.f,0.f,0.f};
    #pragma unroll
    for (int kc = 0; kc < 8; kc++){
      int ph = kc & 1;
      if (kc < 7) asm volatile("s_waitcnt vmcnt(2)" ::: "memory");
      else        asm volatile("s_waitcnt vmcnt(0)" ::: "memory");
      short8 af[2], bf[2];
      #pragma unroll
      for (int i=0;i<2;i++)
        af[i] = *(const short8*)&buf[(i*16 + r16)*LSTR + kc*32 + qd*8];
      #pragma unroll
      for (int j=0;j<2;j++)
        bf[j] = *(const short8*)&wst[ph][w][j][lane*8];
      #pragma unroll
      for (int i=0;i<2;i++)
        #pragma unroll
        for (int j=0;j<2;j++)
          acc[i][j] = __builtin_amdgcn_mfma_f32_16x16x32_bf16(af[i], bf[j], acc[i][j], 0, 0, 0);
      if (kc + 2 < 8){
        asm volatile("s_waitcnt lgkmcnt(0)" ::: "memory");  // ring reads done before overwrite
        STAGE(P, kc + 2, ph);
      }
    }
  };

  GEMM(W1P, false);

  // prefetch W2 kc0/1 into the rings; L2 latency hides under ELU (barrier drains = ready)
  asm volatile("s_waitcnt lgkmcnt(0)" ::: "memory");
  STAGE(W2P, 0, 0); STAGE(W2P, 1, 1);
  __syncthreads();   // all GEMM1 buf reads done -> safe to overwrite buf

  // ---- ELU -> t tile in same LDS ----
  #pragma unroll
  for (int i=0;i<2;i++){
    #pragma unroll
    for (int j=0;j<2;j++){
      int col = w*32 + j*16 + r16;
      #pragma unroll
      for (int rr=0;rr<4;rr++){
        int row = i*16 + qd*4 + rr;
        float v = acc[i][j][rr] + bb1[j];
        v = v > 0.f ? v : (__expf(v) - 1.0f);
        buf[row * LSTR + col] = f2bf(v);
      }
    }
  }
  __syncthreads();

  GEMM(W2P, true);

  // ---- epilogue ----
  #pragma unroll
  for (int i=0;i<2;i++){
    #pragma unroll
    for (int j=0;j<2;j++){
      int col = w*32 + j*16 + r16;
      #pragma unroll
      for (int rr=0;rr<4;rr++){
        size_t row = row0 + i*16 + qd*4 + rr;
        hfeat[row * 256 + col] = f2bf(acc[i][j][rr] + bb2[j]);
      }
    }
  }
}

// ================= LSTM layer: gates GEMM (K-split x4 waves) + fused cell =================
// 128 blocks x 256 (R4-exact: the measured-best lstm; (256,1)/templated-unroll regressed).
__global__ __launch_bounds__(256) void lstm_layer(const ushort_t* __restrict__ A, int lda,
    const ushort_t* __restrict__ WcP, const float* __restrict__ bcp, int KC,
    float* __restrict__ c, ushort_t* __restrict__ dstA, int sA,
    ushort_t* __restrict__ dstB, int sB, float* __restrict__ qdst)
{
  __shared__ float sbuf[3][4][256];
  int tid = threadIdx.x, w = tid >> 6, lane = tid & 63, qd = lane >> 4, r16 = lane & 15;
  int m0 = (blockIdx.x & 7) * 16, nt = blockIdx.x >> 3;
  int kcq = KC >> 2;                       // chunks per wave: 6 (K=768) or 4 (K=512)
  int kc0 = w * kcq;

  floatx4 acc[4];
  #pragma unroll
  for (int g=0; g<4; g++) acc[g] = (floatx4){0.f,0.f,0.f,0.f};

  const ushort_t* Ar = A + (size_t)(m0 + r16) * lda + qd * 8;
  for (int kc = kc0; kc < kc0 + kcq; kc++){
    short8 av = *(const short8*)(Ar + kc*32);
    #pragma unroll
    for (int g = 0; g < 4; g++){
      short8 bv = *(const short8*)(WcP + (size_t)((((g*16 + nt)*KC) + kc)*64 + lane)*8);
      acc[g] = __builtin_amdgcn_mfma_f32_16x16x32_bf16(av, bv, acc[g], 0, 0, 0);
    }
  }
  if (w){
    #pragma unroll
    for (int g=0; g<4; g++) *(floatx4*)&sbuf[w-1][g][lane*4] = acc[g];
  }
  __syncthreads();
  if (w == 0){
    #pragma unroll
    for (int g=0; g<4; g++)
      #pragma unroll
      for (int t=0; t<3; t++){
        floatx4 p = *(floatx4*)&sbuf[t][g][lane*4];
        acc[g] = acc[g] + p;
      }
    int h = nt*16 + r16;
    float bci = bcp[h], bcf = bcp[256+h], bcg = bcp[512+h], bco = bcp[768+h];
    #pragma unroll
    for (int rr=0; rr<4; rr++){
      int row = m0 + qd*4 + rr;
      float gi = acc[0][rr] + bci;
      float gf = acc[1][rr] + bcf;
      float gg = acc[2][rr] + bcg;
      float go = acc[3][rr] + bco;
      float cp = c[row*256 + h];
      float cn = sigf(gf)*cp + sigf(gi)*tanhf(gg);
      float hn = sigf(go)*tanhf(cn);
      c[row*256 + h] = cn;
      ushort_t hb = f2bf(hn);
      dstA[row*sA + h] = hb;
      dstB[row*sB + h] = hb;
      if (qdst) qdst[row*512 + h] = hn;
    }
  }
}

// ======== segment-owned attention + folded finalize (last-block-arrives pattern) ========
// 1024 blocks x 256 thr; block = (segment b = blockIdx>>3, eighth p = blockIdx&7) via seg[].
// Partial phase is R4-exact (2-chain shfl, depth-2 pair prefetch, no atomic accumulation).
// Then: stores -> threadfence -> atomicAdd(cnt[b]); the 8th-arriving block acquires, sums
// the 8 partials, writes q_star/xc0 r-halves, resets cnt, and (last step) does the output
// GEMV. Deterministic — no spin, no co-residency assumption. Kills 5 attn_fin dispatches.
__global__ __launch_bounds__(256) void attn_onepass(const ushort_t* __restrict__ hfeat,
    const int* __restrict__ seg, float* __restrict__ q_star,
    float* __restrict__ r_part, float* __restrict__ z_part,
    ushort_t* __restrict__ xc0, const float* __restrict__ outW,
    const float* __restrict__ outb, float* __restrict__ out,
    unsigned int* __restrict__ cnt, int last)
{
  __shared__ float sred[4][260];
  __shared__ float qs[512];
  __shared__ int lastb;
  int b = blockIdx.x >> 3, p = blockIdx.x & 7;
  int w = threadIdx.x >> 6, lane = threadIdx.x & 63;
  int s0 = seg[b], s1 = seg[b+1], len = s1 - s0;
  int q0 = s0 + ((len * p) >> 3);
  int q1 = s0 + ((len * (p+1)) >> 3);

  float S0=0.f, S1=0.f, S2=0.f, S3=0.f, Z=0.f;

  int n = q0 + w;
  if (n < q1){
    float4 q = *(const float4*)(q_star + (size_t)b*512 + lane*4);
    #define LOADH(nn) (*(const ushort4*)(hfeat + (size_t)(nn)*256 + lane*4))
    ushort4 ha = LOADH(n);
    ushort4 hb = ha;
    if (n + 4 < q1) hb = LOADH(n + 4);
    for (; n < q1; n += 8){
      // prefetch next pair (wave-uniform guards)
      ushort4 hc = ha, hd = hb;
      if (n + 8  < q1) hc = LOADH(n + 8);
      if (n + 12 < q1) hd = LOADH(n + 12);
      // two independent dot+reduce chains
      float a0=bf2f(ha.x), a1=bf2f(ha.y), a2=bf2f(ha.z), a3=bf2f(ha.w);
      float da = a0*q.x + a1*q.y + a2*q.z + a3*q.w;
      float b0=0.f,b1=0.f,b2=0.f,b3=0.f, db=0.f;
      int vB = (n + 4) < q1;
      if (vB){
        b0=bf2f(hb.x); b1=bf2f(hb.y); b2=bf2f(hb.z); b3=bf2f(hb.w);
        db = b0*q.x + b1*q.y + b2*q.z + b3*q.w;
      }
      #pragma unroll
      for (int off = 32; off; off >>= 1){
        da += __shfl_xor(da, off);
        db += __shfl_xor(db, off);
      }
      float wa = __expf(da);
      Z += wa; S0 += wa*a0; S1 += wa*a1; S2 += wa*a2; S3 += wa*a3;
      if (vB){
        float wb = __expf(db);
        Z += wb; S0 += wb*b0; S1 += wb*b1; S2 += wb*b2; S3 += wb*b3;
      }
      ha = hc; hb = hd;
    }
    #undef LOADH
  }

  // block reduce (4 waves) -> one partial store, no atomics
  *(float4*)&sred[w][lane*4] = (float4){S0, S1, S2, S3};
  if (lane == 0) sred[w][256] = Z;
  __syncthreads();
  int f = threadIdx.x;
  {
    float v = sred[0][f] + sred[1][f] + sred[2][f] + sred[3][f];
    r_part[((size_t)p*128 + b)*256 + f] = v;
    if (f == 0)
      z_part[p*128 + b] = sred[0][256] + sred[1][256] + sred[2][256] + sred[3][256];
  }

  // ---- release our partial, count arrivals ----
  __threadfence();
  __syncthreads();
  if (f == 0){
    unsigned int old = atomicAdd(&cnt[b], 1u);
    lastb = (old == 7u);
  }
  __syncthreads();
  if (!lastb) return;

  // ---- we are the 8th block of segment b: acquire + finalize ----
  __threadfence();
  float s = 0.f, z = 0.f;
  #pragma unroll
  for (int t = 0; t < 8; t++){
    s += r_part[((size_t)(t*128 + b))*256 + f];
    z += z_part[t*128 + b];
  }
  float v = s / (z + 1e-16f);
  q_star[b*512 + 256 + f] = v;
  xc0[b*768 + 256 + f] = f2bf(v);
  if (f == 0) atomicExch(&cnt[b], 0u);   // reset for next step (stream-ordered reuse)
  if (last){
    qs[f] = q_star[b*512 + f];     // q half (written by lstm2, prior dispatch)
    qs[256 + f] = v;               // r half (computed here)
    __syncthreads();
    if (f < 128){
      float acc = outb[f];
      for (int k = 0; k < 512; k++) acc += qs[k] * outW[k*128 + f];
      out[b*128 + f] = acc;
    }
  }
}

// ================= prep: fragment-major weight packing + all zero/init =================
// Packed layout per 16-col tile T, 32-k chunk kc: [(T*KC + kc)*64 + lane]*8 + j,
// where lane holds BT[n = T*16 + (lane&15)][k = kc*32 + (lane>>4)*8 + j].
__global__ void prep_all(const float* __restrict__ W1, const float* __restrict__ W2,
    const float* __restrict__ Wih0, const float* __restrict__ Whh0,
    const float* __restrict__ Wih1, const float* __restrict__ Whh1,
    const float* __restrict__ Wih2, const float* __restrict__ Whh2,
    const float* __restrict__ bih0, const float* __restrict__ bhh0,
    const float* __restrict__ bih1, const float* __restrict__ bhh1,
    const float* __restrict__ bih2, const float* __restrict__ bhh2,
    const int* __restrict__ bidx,
    ushort_t* __restrict__ W1P, ushort_t* __restrict__ W2P,
    ushort_t* __restrict__ Wc0P, ushort_t* __restrict__ Wc1P, ushort_t* __restrict__ Wc2P,
    float* __restrict__ c, ushort_t* __restrict__ xc, float* __restrict__ q_star,
    float* __restrict__ bc, int* __restrict__ seg, unsigned int* __restrict__ cnt)
{
  int i = blockIdx.x*256 + threadIdx.x;
  // --- W1P / W2P: K=256, KC=8, tile size 4096 ---
  if (i < 131072){
    const float* W = (i < 65536) ? W1 : W2;
    ushort_t* P = (i < 65536) ? W1P : W2P;
    int r = i & 65535;
    int T = r >> 12, r2 = r & 4095;
    int kc = r2 >> 9, l = (r2 >> 3) & 63, j = r2 & 7;
    int k = kc*32 + ((l>>4)<<3) + j;
    int n = T*16 + (l & 15);
    P[r] = f2bf(W[k*256 + n]);
    return;
  }
  i -= 131072;
  // --- Wc0P: K=768, KC=24, tile size 12288, 64 tiles ---
  if (i < 786432){
    int T = i / 12288, r2 = i - T*12288;
    int kc = r2 >> 9, l = (r2 >> 3) & 63, j = r2 & 7;
    int k = kc*32 + ((l>>4)<<3) + j;
    int g = T >> 4, n = (T & 15)*16 + (l & 15);
    int row = g*256 + n;
    Wc0P[i] = f2bf(k < 512 ? Wih0[row*512 + k] : Whh0[row*256 + (k - 512)]);
    return;
  }
  i -= 786432;
  // --- Wc1P / Wc2P: K=512, KC=16, tile size 8192, 64 tiles each ---
  if (i < 1048576){
    const float* Wih = (i < 524288) ? Wih1 : Wih2;
    const float* Whh = (i < 524288) ? Whh1 : Whh2;
    ushort_t* P = (i < 524288) ? Wc1P : Wc2P;
    int r = i & 524287;
    int T = r >> 13, r2 = r & 8191;
    int kc = r2 >> 9, l = (r2 >> 3) & 63, j = r2 & 7;
    int k = kc*32 + ((l>>4)<<3) + j;
    int g = T >> 4, n = (T & 15)*16 + (l & 15);
    int row = g*256 + n;
    P[r] = f2bf(k < 256 ? Wih[row*256 + k] : Whh[row*256 + (k - 256)]);
    return;
  }
  i -= 1048576;
  if (i < 98304) { c[i] = 0.f; return; }
  i -= 98304;
  if (i < 229376) { xc[i] = 0; return; }
  i -= 229376;
  if (i < 65536) { q_star[i] = 0.f; return; }
  i -= 65536;
  if (i < 3072) {
    int l = i >> 10, g = i & 1023;
    const float* bi = (l == 0) ? bih0 : ((l == 1) ? bih1 : bih2);
    const float* bh = (l == 0) ? bhh0 : ((l == 1) ? bhh1 : bhh2);
    bc[i] = bi[g] + bh[g];
    return;
  }
  i -= 3072;
  if (i < 129) {
    int lo = 0, hi = NN;
    while (lo < hi){ int mid = (lo + hi) >> 1; if (bidx[mid] < i) lo = mid + 1; else hi = mid; }
    seg[i] = lo;
    return;
  }
  i -= 129;
  if (i < 128) cnt[i] = 0u;
}

extern "C" void kernel_launch(void* const* d_in, const int* in_sizes, int n_in,
                              void* d_out, int out_size, void* d_ws, size_t ws_size,
                              hipStream_t stream)
{
  const float* x    = (const float*)d_in[0];
  const int*   bidx = (const int*)  d_in[1];
  const float* W1   = (const float*)d_in[2];
  const float* b1   = (const float*)d_in[3];
  const float* W2   = (const float*)d_in[4];
  const float* b2   = (const float*)d_in[5];
  const float* Wih0 = (const float*)d_in[6];
  const float* Whh0 = (const float*)d_in[7];
  const float* bih0 = (const float*)d_in[8];
  const float* bhh0 = (const float*)d_in[9];
  const float* Wih1 = (const float*)d_in[10];
  const float* Whh1 = (const float*)d_in[11];
  const float* bih1 = (const float*)d_in[12];
  const float* bhh1 = (const float*)d_in[13];
  const float* Wih2 = (const float*)d_in[14];
  const float* Whh2 = (const float*)d_in[15];
  const float* bih2 = (const float*)d_in[16];
  const float* bhh2 = (const float*)d_in[17];
  const float* outW = (const float*)d_in[18];
  const float* outb = (const float*)d_in[19];

  char* p = (char*)d_ws;
  auto alloc = [&](size_t bytes)->char*{ char* r = p; p += (bytes + 255) & ~(size_t)255; return r; };
  ushort_t* hfeat  = (ushort_t*)alloc((size_t)NN*256*2);   // bf16 node features
  ushort_t* W1P    = (ushort_t*)alloc(65536*2);
  ushort_t* W2P    = (ushort_t*)alloc(65536*2);
  ushort_t* Wc0P   = (ushort_t*)alloc(786432*2);
  ushort_t* Wc1P   = (ushort_t*)alloc(524288*2);
  ushort_t* Wc2P   = (ushort_t*)alloc(524288*2);
  float*    bc     = (float*)   alloc(3072*4);
  float*    c_all  = (float*)   alloc(98304*4);
  ushort_t* xc     = (ushort_t*)alloc(229376*2);           // xc0(128x768)|xc1(128x512)|xc2(128x512)
  float*    q_star = (float*)   alloc(65536*4);            // (128,512) fp32
  float*    r_part = (float*)   alloc(8*128*256*4);        // per-eighth attention partials
  float*    z_part = (float*)   alloc(8*128*4);
  int*      seg    = (int*)     alloc(129*4);
  unsigned int* cnt = (unsigned int*)alloc(128*4);         // per-segment arrival counters

  ushort_t* xc0 = xc;
  ushort_t* xc1 = xc + 98304;
  ushort_t* xc2 = xc + 163840;
  float* c0 = c_all, *c1 = c_all + 32768, *c2 = c_all + 65536;
  float* bc0 = bc, *bc1 = bc + 1024, *bc2 = bc + 2048;

  prep_all<<<9230, 256, 0, stream>>>(W1, W2, Wih0, Whh0, Wih1, Whh1, Wih2, Whh2,
                                     bih0, bhh0, bih1, bhh1, bih2, bhh2, bidx,
                                     W1P, W2P, Wc0P, Wc1P, Wc2P,
                                     c_all, xc, q_star, bc, seg, cnt);

  fnn_fused<<<3125, 512, 0, stream>>>(x, W1P, b1, W2P, b2, hfeat, NN);

  for (int s = 0; s < NSTEP; s++){
    // layer 0: in = [q | r | h0_prev] (K=768, KC=24)
    lstm_layer<<<128, 256, 0, stream>>>(xc0, 768, Wc0P, bc0, 24, c0, xc0 + 512, 768, xc1, 512, nullptr);
    // layer 1: in = [h0 | h1_prev] (K=512, KC=16)
    lstm_layer<<<128, 256, 0, stream>>>(xc1, 512, Wc1P, bc1, 16, c1, xc1 + 256, 512, xc2, 512, nullptr);
    // layer 2: in = [h1 | h2_prev] (K=512); h2 = q
    lstm_layer<<<128, 256, 0, stream>>>(xc2, 512, Wc2P, bc2, 16, c2, xc2 + 256, 512, xc0, 768, q_star);
    // attention + folded finalize (8th-arriving block per segment finalizes; last step
    // also does the output GEMV)
    attn_onepass<<<1024, 256, 0, stream>>>(hfeat, seg, q_star, r_part, z_part,
                                           xc0, outW, outb, (float*)d_out, cnt,
                                           s == NSTEP-1 ? 1 : 0);
  }
}

// Round 11
// 404.304 us; speedup vs baseline: 2.2610x; 2.2610x over previous
//
#include <hip/hip_runtime.h>

#define NN 100000
#define NSTEP 5
#define LSTR 264   // ushorts; 528B rows, 16B aligned for ds_read_b128

typedef unsigned short ushort_t;
typedef __attribute__((ext_vector_type(8))) short short8;
typedef __attribute__((ext_vector_type(4))) float floatx4;

__device__ __forceinline__ ushort_t f2bf(float f){
  union { float f; unsigned u; } v; v.f = f;
  unsigned r = v.u + 0x7fffu + ((v.u >> 16) & 1u);
  return (ushort_t)(r >> 16);
}
__device__ __forceinline__ float bf2f(ushort_t s){
  union { unsigned u; float f; } v; v.u = ((unsigned)s) << 16;
  return v.f;
}
__device__ __forceinline__ float sigf(float x){ return 1.0f/(1.0f+__expf(-x)); }

// ================= fused FNN: hfeat = (elu(x@W1+b1))@W2+b2, bf16 out =================
// R7-exact (measured best: 75.4us, occ 55%). 3125 blocks x 512 thr, 32 rows x 256 cols.
// Weight pipelining via global_load_lds + counted vmcnt; per-wave private depth-2 ring, no
// barriers in the pipeline.
__global__ __launch_bounds__(512) void fnn_fused(const float* __restrict__ x,
    const ushort_t* __restrict__ W1P, const float* __restrict__ b1,
    const ushort_t* __restrict__ W2P, const float* __restrict__ b2,
    ushort_t* __restrict__ hfeat, int M)
{
  __shared__ ushort_t buf[32 * LSTR];
  __shared__ ushort_t wst[2][8][2][512];   // [phase][wave][j][1KB chunk]
  int tid = threadIdx.x;
  int w = tid >> 6, lane = tid & 63, qd = lane >> 4, r16 = lane & 15;
  size_t row0 = (size_t)blockIdx.x * 32;

  typedef __attribute__((address_space(3))) unsigned int lds_u32;
  typedef __attribute__((address_space(1))) const unsigned int glb_u32;

  // hoisted biases (complete at the staging barrier -> vmcnt slate clean for the pipeline)
  float bb1[2], bb2[2];
  #pragma unroll
  for (int j = 0; j < 2; j++){
    int col = w*32 + j*16 + r16;
    bb1[j] = b1[col];
    bb2[j] = b2[col];
  }

  // ---- stage x tile (32x256 fp32 -> bf16 LDS) ----
  {
    float4 xv[4];
    #pragma unroll
    for (int it = 0; it < 4; it++){
      int idx = it * 512 + tid;
      xv[it] = *(const float4*)(x + (row0 + (idx >> 6)) * 256 + (idx & 63) * 4);
    }
    #pragma unroll
    for (int it = 0; it < 4; it++){
      int idx = it * 512 + tid;
      ushort4 pk = make_ushort4(f2bf(xv[it].x), f2bf(xv[it].y), f2bf(xv[it].z), f2bf(xv[it].w));
      *(ushort4*)&buf[(idx >> 6) * LSTR + (idx & 63) * 4] = pk;
    }
  }
  __syncthreads();   // x-tile visible; all prior vmem drained (clean FIFO)

  auto STAGE = [&](const ushort_t* __restrict__ P, int kc, int ph){
    #pragma unroll
    for (int j = 0; j < 2; j++){
      const ushort_t* gp = P + (size_t)(((w*2 + j)*8 + kc)*512) + lane*8;
      __builtin_amdgcn_global_load_lds((glb_u32*)gp, (lds_u32*)&wst[ph][w][j][0], 16, 0, 0);
    }
  };

  floatx4 acc[2][2];

  auto GEMM = [&](const ushort_t* __restrict__ P, bool prestaged){
    if (!prestaged){ STAGE(P, 0, 0); STAGE(P, 1, 1); }
    #pragma unroll
    for (int i=0;i<2;i++)
      #pragma unroll
      for (int j=0;j<2;j++) acc[i][j] = (floatx4){0.f,0.f,0.f,0.f};
    #pragma unroll
    for (int kc = 0; kc < 8; kc++){
      int ph = kc & 1;
      if (kc < 7) asm volatile("s_waitcnt vmcnt(2)" ::: "memory");
      else        asm volatile("s_waitcnt vmcnt(0)" ::: "memory");
      short8 af[2], bf[2];
      #pragma unroll
      for (int i=0;i<2;i++)
        af[i] = *(const short8*)&buf[(i*16 + r16)*LSTR + kc*32 + qd*8];
      #pragma unroll
      for (int j=0;j<2;j++)
        bf[j] = *(const short8*)&wst[ph][w][j][lane*8];
      #pragma unroll
      for (int i=0;i<2;i++)
        #pragma unroll
        for (int j=0;j<2;j++)
          acc[i][j] = __builtin_amdgcn_mfma_f32_16x16x32_bf16(af[i], bf[j], acc[i][j], 0, 0, 0);
      if (kc + 2 < 8){
        asm volatile("s_waitcnt lgkmcnt(0)" ::: "memory");  // ring reads done before overwrite
        STAGE(P, kc + 2, ph);
      }
    }
  };

  GEMM(W1P, false);

  // prefetch W2 kc0/1 into the rings; L2 latency hides under ELU (barrier drains = ready)
  asm volatile("s_waitcnt lgkmcnt(0)" ::: "memory");
  STAGE(W2P, 0, 0); STAGE(W2P, 1, 1);
  __syncthreads();   // all GEMM1 buf reads done -> safe to overwrite buf

  // ---- ELU -> t tile in same LDS ----
  #pragma unroll
  for (int i=0;i<2;i++){
    #pragma unroll
    for (int j=0;j<2;j++){
      int col = w*32 + j*16 + r16;
      #pragma unroll
      for (int rr=0;rr<4;rr++){
        int row = i*16 + qd*4 + rr;
        float v = acc[i][j][rr] + bb1[j];
        v = v > 0.f ? v : (__expf(v) - 1.0f);
        buf[row * LSTR + col] = f2bf(v);
      }
    }
  }
  __syncthreads();

  GEMM(W2P, true);

  // ---- epilogue ----
  #pragma unroll
  for (int i=0;i<2;i++){
    #pragma unroll
    for (int j=0;j<2;j++){
      int col = w*32 + j*16 + r16;
      #pragma unroll
      for (int rr=0;rr<4;rr++){
        size_t row = row0 + i*16 + qd*4 + rr;
        hfeat[row * 256 + col] = f2bf(acc[i][j][rr] + bb2[j]);
      }
    }
  }
}

// ================= LSTM layer: gates GEMM (K-split x4 waves) + fused cell =================
// 128 blocks x 256 (R4-exact: the measured-best lstm).
__global__ __launch_bounds__(256) void lstm_layer(const ushort_t* __restrict__ A, int lda,
    const ushort_t* __restrict__ WcP, const float* __restrict__ bcp, int KC,
    float* __restrict__ c, ushort_t* __restrict__ dstA, int sA,
    ushort_t* __restrict__ dstB, int sB, float* __restrict__ qdst)
{
  __shared__ float sbuf[3][4][256];
  int tid = threadIdx.x, w = tid >> 6, lane = tid & 63, qd = lane >> 4, r16 = lane & 15;
  int m0 = (blockIdx.x & 7) * 16, nt = blockIdx.x >> 3;
  int kcq = KC >> 2;                       // chunks per wave: 6 (K=768) or 4 (K=512)
  int kc0 = w * kcq;

  floatx4 acc[4];
  #pragma unroll
  for (int g=0; g<4; g++) acc[g] = (floatx4){0.f,0.f,0.f,0.f};

  const ushort_t* Ar = A + (size_t)(m0 + r16) * lda + qd * 8;
  for (int kc = kc0; kc < kc0 + kcq; kc++){
    short8 av = *(const short8*)(Ar + kc*32);
    #pragma unroll
    for (int g = 0; g < 4; g++){
      short8 bv = *(const short8*)(WcP + (size_t)((((g*16 + nt)*KC) + kc)*64 + lane)*8);
      acc[g] = __builtin_amdgcn_mfma_f32_16x16x32_bf16(av, bv, acc[g], 0, 0, 0);
    }
  }
  if (w){
    #pragma unroll
    for (int g=0; g<4; g++) *(floatx4*)&sbuf[w-1][g][lane*4] = acc[g];
  }
  __syncthreads();
  if (w == 0){
    #pragma unroll
    for (int g=0; g<4; g++)
      #pragma unroll
      for (int t=0; t<3; t++){
        floatx4 p = *(floatx4*)&sbuf[t][g][lane*4];
        acc[g] = acc[g] + p;
      }
    int h = nt*16 + r16;
    float bci = bcp[h], bcf = bcp[256+h], bcg = bcp[512+h], bco = bcp[768+h];
    #pragma unroll
    for (int rr=0; rr<4; rr++){
      int row = m0 + qd*4 + rr;
      float gi = acc[0][rr] + bci;
      float gf = acc[1][rr] + bcf;
      float gg = acc[2][rr] + bcg;
      float go = acc[3][rr] + bco;
      float cp = c[row*256 + h];
      float cn = sigf(gf)*cp + sigf(gi)*tanhf(gg);
      float hn = sigf(go)*tanhf(cn);
      c[row*256 + h] = cn;
      ushort_t hb = f2bf(hn);
      dstA[row*sA + h] = hb;
      dstB[row*sB + h] = hb;
      if (qdst) qdst[row*512 + h] = hn;
    }
  }
}

// ================= segment-owned attention: no atomics, no fences, no bidx =================
// 2048 blocks x 256 thr; block = (segment b = blockIdx>>4, sixteenth p = blockIdx&15) via
// seg[]. R10 proved device-scope fences inside this streaming kernel nuke L2 (150us); the
// dispatch boundary IS the sync. 16-way split doubles resident waves vs R8's 8-way for
// latency hiding. Partial phase otherwise R4/R8-exact (2-chain shfl, depth-2 pair prefetch).
__global__ __launch_bounds__(256) void attn_onepass(const ushort_t* __restrict__ hfeat,
    const int* __restrict__ seg, const float* __restrict__ q_star,
    float* __restrict__ r_part, float* __restrict__ z_part)
{
  __shared__ float sred[4][260];
  int b = blockIdx.x >> 4, p = blockIdx.x & 15;
  int w = threadIdx.x >> 6, lane = threadIdx.x & 63;
  int s0 = seg[b], s1 = seg[b+1], len = s1 - s0;
  int q0 = s0 + ((len * p) >> 4);
  int q1 = s0 + ((len * (p+1)) >> 4);

  float S0=0.f, S1=0.f, S2=0.f, S3=0.f, Z=0.f;

  int n = q0 + w;
  if (n < q1){
    float4 q = *(const float4*)(q_star + (size_t)b*512 + lane*4);
    #define LOADH(nn) (*(const ushort4*)(hfeat + (size_t)(nn)*256 + lane*4))
    ushort4 ha = LOADH(n);
    ushort4 hb = ha;
    if (n + 4 < q1) hb = LOADH(n + 4);
    for (; n < q1; n += 8){
      // prefetch next pair (wave-uniform guards)
      ushort4 hc = ha, hd = hb;
      if (n + 8  < q1) hc = LOADH(n + 8);
      if (n + 12 < q1) hd = LOADH(n + 12);
      // two independent dot+reduce chains
      float a0=bf2f(ha.x), a1=bf2f(ha.y), a2=bf2f(ha.z), a3=bf2f(ha.w);
      float da = a0*q.x + a1*q.y + a2*q.z + a3*q.w;
      float b0=0.f,b1=0.f,b2=0.f,b3=0.f, db=0.f;
      int vB = (n + 4) < q1;
      if (vB){
        b0=bf2f(hb.x); b1=bf2f(hb.y); b2=bf2f(hb.z); b3=bf2f(hb.w);
        db = b0*q.x + b1*q.y + b2*q.z + b3*q.w;
      }
      #pragma unroll
      for (int off = 32; off; off >>= 1){
        da += __shfl_xor(da, off);
        db += __shfl_xor(db, off);
      }
      float wa = __expf(da);
      Z += wa; S0 += wa*a0; S1 += wa*a1; S2 += wa*a2; S3 += wa*a3;
      if (vB){
        float wb = __expf(db);
        Z += wb; S0 += wb*b0; S1 += wb*b1; S2 += wb*b2; S3 += wb*b3;
      }
      ha = hc; hb = hd;
    }
    #undef LOADH
  }

  // block reduce (4 waves) -> one partial store, no atomics
  *(float4*)&sred[w][lane*4] = (float4){S0, S1, S2, S3};
  if (lane == 0) sred[w][256] = Z;
  __syncthreads();
  int f = threadIdx.x;
  if (f < 256){
    float v = sred[0][f] + sred[1][f] + sred[2][f] + sred[3][f];
    r_part[((size_t)p*128 + b)*256 + f] = v;
    if (f == 0)
      z_part[p*128 + b] = sred[0][256] + sred[1][256] + sred[2][256] + sred[3][256];
  }
}

// ================= finalize: r = sum(partials)/Z -> q_star/xc0; last: output GEMM =========
__global__ __launch_bounds__(256) void attn_fin(const float* __restrict__ r_part,
    const float* __restrict__ z_part, float* __restrict__ q_star, ushort_t* __restrict__ xc0,
    const float* __restrict__ outW, const float* __restrict__ outb,
    float* __restrict__ out, int last)
{
  __shared__ float qs[512];
  int b = blockIdx.x, f = threadIdx.x;
  float s = 0.f, z = 0.f;
  #pragma unroll
  for (int t = 0; t < 16; t++){
    s += r_part[((size_t)(t*128 + b))*256 + f];
    z += z_part[t*128 + b];
  }
  float v = s / (z + 1e-16f);
  q_star[b*512 + 256 + f] = v;
  xc0[b*768 + 256 + f] = f2bf(v);
  if (last){
    qs[f] = q_star[b*512 + f];     // q half (written by lstm2, prior dispatch)
    qs[256 + f] = v;               // r half (computed here)
    __syncthreads();
    if (f < 128){
      float acc = outb[f];
      for (int k = 0; k < 512; k++) acc += qs[k] * outW[k*128 + f];
      out[b*128 + f] = acc;
    }
  }
}

// ================= prep: fragment-major weight packing + all zero/init =================
// Packed layout per 16-col tile T, 32-k chunk kc: [(T*KC + kc)*64 + lane]*8 + j,
// where lane holds BT[n = T*16 + (lane&15)][k = kc*32 + (lane>>4)*8 + j].
__global__ void prep_all(const float* __restrict__ W1, const float* __restrict__ W2,
    const float* __restrict__ Wih0, const float* __restrict__ Whh0,
    const float* __restrict__ Wih1, const float* __restrict__ Whh1,
    const float* __restrict__ Wih2, const float* __restrict__ Whh2,
    const float* __restrict__ bih0, const float* __restrict__ bhh0,
    const float* __restrict__ bih1, const float* __restrict__ bhh1,
    const float* __restrict__ bih2, const float* __restrict__ bhh2,
    const int* __restrict__ bidx,
    ushort_t* __restrict__ W1P, ushort_t* __restrict__ W2P,
    ushort_t* __restrict__ Wc0P, ushort_t* __restrict__ Wc1P, ushort_t* __restrict__ Wc2P,
    float* __restrict__ c, ushort_t* __restrict__ xc, float* __restrict__ q_star,
    float* __restrict__ bc, int* __restrict__ seg)
{
  int i = blockIdx.x*256 + threadIdx.x;
  // --- W1P / W2P: K=256, KC=8, tile size 4096 ---
  if (i < 131072){
    const float* W = (i < 65536) ? W1 : W2;
    ushort_t* P = (i < 65536) ? W1P : W2P;
    int r = i & 65535;
    int T = r >> 12, r2 = r & 4095;
    int kc = r2 >> 9, l = (r2 >> 3) & 63, j = r2 & 7;
    int k = kc*32 + ((l>>4)<<3) + j;
    int n = T*16 + (l & 15);
    P[r] = f2bf(W[k*256 + n]);
    return;
  }
  i -= 131072;
  // --- Wc0P: K=768, KC=24, tile size 12288, 64 tiles ---
  if (i < 786432){
    int T = i / 12288, r2 = i - T*12288;
    int kc = r2 >> 9, l = (r2 >> 3) & 63, j = r2 & 7;
    int k = kc*32 + ((l>>4)<<3) + j;
    int g = T >> 4, n = (T & 15)*16 + (l & 15);
    int row = g*256 + n;
    Wc0P[i] = f2bf(k < 512 ? Wih0[row*512 + k] : Whh0[row*256 + (k - 512)]);
    return;
  }
  i -= 786432;
  // --- Wc1P / Wc2P: K=512, KC=16, tile size 8192, 64 tiles each ---
  if (i < 1048576){
    const float* Wih = (i < 524288) ? Wih1 : Wih2;
    const float* Whh = (i < 524288) ? Whh1 : Whh2;
    ushort_t* P = (i < 524288) ? Wc1P : Wc2P;
    int r = i & 524287;
    int T = r >> 13, r2 = r & 8191;
    int kc = r2 >> 9, l = (r2 >> 3) & 63, j = r2 & 7;
    int k = kc*32 + ((l>>4)<<3) + j;
    int g = T >> 4, n = (T & 15)*16 + (l & 15);
    int row = g*256 + n;
    P[r] = f2bf(k < 256 ? Wih[row*256 + k] : Whh[row*256 + (k - 256)]);
    return;
  }
  i -= 1048576;
  if (i < 98304) { c[i] = 0.f; return; }
  i -= 98304;
  if (i < 229376) { xc[i] = 0; return; }
  i -= 229376;
  if (i < 65536) { q_star[i] = 0.f; return; }
  i -= 65536;
  if (i < 3072) {
    int l = i >> 10, g = i & 1023;
    const float* bi = (l == 0) ? bih0 : ((l == 1) ? bih1 : bih2);
    const float* bh = (l == 0) ? bhh0 : ((l == 1) ? bhh1 : bhh2);
    bc[i] = bi[g] + bh[g];
    return;
  }
  i -= 3072;
  if (i < 129) {
    int lo = 0, hi = NN;
    while (lo < hi){ int mid = (lo + hi) >> 1; if (bidx[mid] < i) lo = mid + 1; else hi = mid; }
    seg[i] = lo;
    return;
  }
}

extern "C" void kernel_launch(void* const* d_in, const int* in_sizes, int n_in,
                              void* d_out, int out_size, void* d_ws, size_t ws_size,
                              hipStream_t stream)
{
  const float* x    = (const float*)d_in[0];
  const int*   bidx = (const int*)  d_in[1];
  const float* W1   = (const float*)d_in[2];
  const float* b1   = (const float*)d_in[3];
  const float* W2   = (const float*)d_in[4];
  const float* b2   = (const float*)d_in[5];
  const float* Wih0 = (const float*)d_in[6];
  const float* Whh0 = (const float*)d_in[7];
  const float* bih0 = (const float*)d_in[8];
  const float* bhh0 = (const float*)d_in[9];
  const float* Wih1 = (const float*)d_in[10];
  const float* Whh1 = (const float*)d_in[11];
  const float* bih1 = (const float*)d_in[12];
  const float* bhh1 = (const float*)d_in[13];
  const float* Wih2 = (const float*)d_in[14];
  const float* Whh2 = (const float*)d_in[15];
  const float* bih2 = (const float*)d_in[16];
  const float* bhh2 = (const float*)d_in[17];
  const float* outW = (const float*)d_in[18];
  const float* outb = (const float*)d_in[19];

  char* p = (char*)d_ws;
  auto alloc = [&](size_t bytes)->char*{ char* r = p; p += (bytes + 255) & ~(size_t)255; return r; };
  ushort_t* hfeat  = (ushort_t*)alloc((size_t)NN*256*2);   // bf16 node features
  ushort_t* W1P    = (ushort_t*)alloc(65536*2);
  ushort_t* W2P    = (ushort_t*)alloc(65536*2);
  ushort_t* Wc0P   = (ushort_t*)alloc(786432*2);
  ushort_t* Wc1P   = (ushort_t*)alloc(524288*2);
  ushort_t* Wc2P   = (ushort_t*)alloc(524288*2);
  float*    bc     = (float*)   alloc(3072*4);
  float*    c_all  = (float*)   alloc(98304*4);
  ushort_t* xc     = (ushort_t*)alloc(229376*2);           // xc0(128x768)|xc1(128x512)|xc2(128x512)
  float*    q_star = (float*)   alloc(65536*4);            // (128,512) fp32
  float*    r_part = (float*)   alloc((size_t)16*128*256*4); // per-sixteenth attention partials
  float*    z_part = (float*)   alloc(16*128*4);
  int*      seg    = (int*)     alloc(129*4);

  ushort_t* xc0 = xc;
  ushort_t* xc1 = xc + 98304;
  ushort_t* xc2 = xc + 163840;
  float* c0 = c_all, *c1 = c_all + 32768, *c2 = c_all + 65536;
  float* bc0 = bc, *bc1 = bc + 1024, *bc2 = bc + 2048;

  prep_all<<<9229, 256, 0, stream>>>(W1, W2, Wih0, Whh0, Wih1, Whh1, Wih2, Whh2,
                                     bih0, bhh0, bih1, bhh1, bih2, bhh2, bidx,
                                     W1P, W2P, Wc0P, Wc1P, Wc2P,
                                     c_all, xc, q_star, bc, seg);

  fnn_fused<<<3125, 512, 0, stream>>>(x, W1P, b1, W2P, b2, hfeat, NN);

  for (int s = 0; s < NSTEP; s++){
    // layer 0: in = [q | r | h0_prev] (K=768, KC=24)
    lstm_layer<<<128, 256, 0, stream>>>(xc0, 768, Wc0P, bc0, 24, c0, xc0 + 512, 768, xc1, 512, nullptr);
    // layer 1: in = [h0 | h1_prev] (K=512, KC=16)
    lstm_layer<<<128, 256, 0, stream>>>(xc1, 512, Wc1P, bc1, 16, c1, xc1 + 256, 512, xc2, 512, nullptr);
    // layer 2: in = [h1 | h2_prev] (K=512); h2 = q
    lstm_layer<<<128, 256, 0, stream>>>(xc2, 512, Wc2P, bc2, 16, c2, xc2 + 256, 512, xc0, 768, q_star);
    // segment-owned attention (16-way split) + finalize (last step folds in output GEMM)
    attn_onepass<<<2048, 256, 0, stream>>>(hfeat, seg, q_star, r_part, z_part);
    attn_fin<<<128, 256, 0, stream>>>(r_part, z_part, q_star, xc0, outW, outb,
                                      (float*)d_out, s == NSTEP-1 ? 1 : 0);
  }
}

// Round 12
// 399.186 us; speedup vs baseline: 2.2900x; 1.0128x over previous
//
#include <hip/hip_runtime.h>

#define NN 100000
#define NSTEP 5
#define LSTR 264   // ushorts; 528B rows, 16B aligned for ds_read_b128

typedef unsigned short ushort_t;
typedef __attribute__((ext_vector_type(8))) short short8;
typedef __attribute__((ext_vector_type(4))) float floatx4;

__device__ __forceinline__ ushort_t f2bf(float f){
  union { float f; unsigned u; } v; v.f = f;
  unsigned r = v.u + 0x7fffu + ((v.u >> 16) & 1u);
  return (ushort_t)(r >> 16);
}
__device__ __forceinline__ float bf2f(ushort_t s){
  union { unsigned u; float f; } v; v.u = ((unsigned)s) << 16;
  return v.f;
}
__device__ __forceinline__ float sigf(float x){ return 1.0f/(1.0f+__expf(-x)); }

// ================= fused FNN: hfeat = (elu(x@W1+b1))@W2+b2, bf16 out =================
// R7-exact (measured best: 74-75us, occ 55%). 3125 blocks x 512 thr, 32 rows x 256 cols.
// Weight pipelining via global_load_lds + counted vmcnt; per-wave private depth-2 ring, no
// barriers in the pipeline.
__global__ __launch_bounds__(512) void fnn_fused(const float* __restrict__ x,
    const ushort_t* __restrict__ W1P, const float* __restrict__ b1,
    const ushort_t* __restrict__ W2P, const float* __restrict__ b2,
    ushort_t* __restrict__ hfeat, int M)
{
  __shared__ ushort_t buf[32 * LSTR];
  __shared__ ushort_t wst[2][8][2][512];   // [phase][wave][j][1KB chunk]
  int tid = threadIdx.x;
  int w = tid >> 6, lane = tid & 63, qd = lane >> 4, r16 = lane & 15;
  size_t row0 = (size_t)blockIdx.x * 32;

  typedef __attribute__((address_space(3))) unsigned int lds_u32;
  typedef __attribute__((address_space(1))) const unsigned int glb_u32;

  // hoisted biases (complete at the staging barrier -> vmcnt slate clean for the pipeline)
  float bb1[2], bb2[2];
  #pragma unroll
  for (int j = 0; j < 2; j++){
    int col = w*32 + j*16 + r16;
    bb1[j] = b1[col];
    bb2[j] = b2[col];
  }

  // ---- stage x tile (32x256 fp32 -> bf16 LDS) ----
  {
    float4 xv[4];
    #pragma unroll
    for (int it = 0; it < 4; it++){
      int idx = it * 512 + tid;
      xv[it] = *(const float4*)(x + (row0 + (idx >> 6)) * 256 + (idx & 63) * 4);
    }
    #pragma unroll
    for (int it = 0; it < 4; it++){
      int idx = it * 512 + tid;
      ushort4 pk = make_ushort4(f2bf(xv[it].x), f2bf(xv[it].y), f2bf(xv[it].z), f2bf(xv[it].w));
      *(ushort4*)&buf[(idx >> 6) * LSTR + (idx & 63) * 4] = pk;
    }
  }
  __syncthreads();   // x-tile visible; all prior vmem drained (clean FIFO)

  auto STAGE = [&](const ushort_t* __restrict__ P, int kc, int ph){
    #pragma unroll
    for (int j = 0; j < 2; j++){
      const ushort_t* gp = P + (size_t)(((w*2 + j)*8 + kc)*512) + lane*8;
      __builtin_amdgcn_global_load_lds((glb_u32*)gp, (lds_u32*)&wst[ph][w][j][0], 16, 0, 0);
    }
  };

  floatx4 acc[2][2];

  auto GEMM = [&](const ushort_t* __restrict__ P, bool prestaged){
    if (!prestaged){ STAGE(P, 0, 0); STAGE(P, 1, 1); }
    #pragma unroll
    for (int i=0;i<2;i++)
      #pragma unroll
      for (int j=0;j<2;j++) acc[i][j] = (floatx4){0.f,0.f,0.f,0.f};
    #pragma unroll
    for (int kc = 0; kc < 8; kc++){
      int ph = kc & 1;
      if (kc < 7) asm volatile("s_waitcnt vmcnt(2)" ::: "memory");
      else        asm volatile("s_waitcnt vmcnt(0)" ::: "memory");
      short8 af[2], bf[2];
      #pragma unroll
      for (int i=0;i<2;i++)
        af[i] = *(const short8*)&buf[(i*16 + r16)*LSTR + kc*32 + qd*8];
      #pragma unroll
      for (int j=0;j<2;j++)
        bf[j] = *(const short8*)&wst[ph][w][j][lane*8];
      #pragma unroll
      for (int i=0;i<2;i++)
        #pragma unroll
        for (int j=0;j<2;j++)
          acc[i][j] = __builtin_amdgcn_mfma_f32_16x16x32_bf16(af[i], bf[j], acc[i][j], 0, 0, 0);
      if (kc + 2 < 8){
        asm volatile("s_waitcnt lgkmcnt(0)" ::: "memory");  // ring reads done before overwrite
        STAGE(P, kc + 2, ph);
      }
    }
  };

  GEMM(W1P, false);

  // prefetch W2 kc0/1 into the rings; L2 latency hides under ELU (barrier drains = ready)
  asm volatile("s_waitcnt lgkmcnt(0)" ::: "memory");
  STAGE(W2P, 0, 0); STAGE(W2P, 1, 1);
  __syncthreads();   // all GEMM1 buf reads done -> safe to overwrite buf

  // ---- ELU -> t tile in same LDS ----
  #pragma unroll
  for (int i=0;i<2;i++){
    #pragma unroll
    for (int j=0;j<2;j++){
      int col = w*32 + j*16 + r16;
      #pragma unroll
      for (int rr=0;rr<4;rr++){
        int row = i*16 + qd*4 + rr;
        float v = acc[i][j][rr] + bb1[j];
        v = v > 0.f ? v : (__expf(v) - 1.0f);
        buf[row * LSTR + col] = f2bf(v);
      }
    }
  }
  __syncthreads();

  GEMM(W2P, true);

  // ---- epilogue ----
  #pragma unroll
  for (int i=0;i<2;i++){
    #pragma unroll
    for (int j=0;j<2;j++){
      int col = w*32 + j*16 + r16;
      #pragma unroll
      for (int rr=0;rr<4;rr++){
        size_t row = row0 + i*16 + qd*4 + rr;
        hfeat[row * 256 + col] = f2bf(acc[i][j][rr] + bb2[j]);
      }
    }
  }
}

// ================= LSTM layer: gates GEMM (K-split x4 waves) + fused cell =================
// 128 blocks x 256 (R4-exact: the measured-best lstm).
__global__ __launch_bounds__(256) void lstm_layer(const ushort_t* __restrict__ A, int lda,
    const ushort_t* __restrict__ WcP, const float* __restrict__ bcp, int KC,
    float* __restrict__ c, ushort_t* __restrict__ dstA, int sA,
    ushort_t* __restrict__ dstB, int sB, float* __restrict__ qdst)
{
  __shared__ float sbuf[3][4][256];
  int tid = threadIdx.x, w = tid >> 6, lane = tid & 63, qd = lane >> 4, r16 = lane & 15;
  int m0 = (blockIdx.x & 7) * 16, nt = blockIdx.x >> 3;
  int kcq = KC >> 2;                       // chunks per wave: 6 (K=768) or 4 (K=512)
  int kc0 = w * kcq;

  floatx4 acc[4];
  #pragma unroll
  for (int g=0; g<4; g++) acc[g] = (floatx4){0.f,0.f,0.f,0.f};

  const ushort_t* Ar = A + (size_t)(m0 + r16) * lda + qd * 8;
  for (int kc = kc0; kc < kc0 + kcq; kc++){
    short8 av = *(const short8*)(Ar + kc*32);
    #pragma unroll
    for (int g = 0; g < 4; g++){
      short8 bv = *(const short8*)(WcP + (size_t)((((g*16 + nt)*KC) + kc)*64 + lane)*8);
      acc[g] = __builtin_amdgcn_mfma_f32_16x16x32_bf16(av, bv, acc[g], 0, 0, 0);
    }
  }
  if (w){
    #pragma unroll
    for (int g=0; g<4; g++) *(floatx4*)&sbuf[w-1][g][lane*4] = acc[g];
  }
  __syncthreads();
  if (w == 0){
    #pragma unroll
    for (int g=0; g<4; g++)
      #pragma unroll
      for (int t=0; t<3; t++){
        floatx4 p = *(floatx4*)&sbuf[t][g][lane*4];
        acc[g] = acc[g] + p;
      }
    int h = nt*16 + r16;
    float bci = bcp[h], bcf = bcp[256+h], bcg = bcp[512+h], bco = bcp[768+h];
    #pragma unroll
    for (int rr=0; rr<4; rr++){
      int row = m0 + qd*4 + rr;
      float gi = acc[0][rr] + bci;
      float gf = acc[1][rr] + bcf;
      float gg = acc[2][rr] + bcg;
      float go = acc[3][rr] + bco;
      float cp = c[row*256 + h];
      float cn = sigf(gf)*cp + sigf(gi)*tanhf(gg);
      float hn = sigf(go)*tanhf(cn);
      c[row*256 + h] = cn;
      ushort_t hb = f2bf(hn);
      dstA[row*sA + h] = hb;
      dstB[row*sB + h] = hb;
      if (qdst) qdst[row*512 + h] = hn;
    }
  }
}

// ============ segment-owned attention: half-wave node pairs, 5-step dual reduce ============
// 2048 blocks x 256 thr; block = (segment b = blockIdx>>4, sixteenth p = blockIdx&15).
// NEW vs R11: lanes 0-31 own node base, lanes 32-63 own node base+1 (8 dims/lane, 16B
// short8 loads). ONE 5-step shfl chain (xor 16..1, stays within each 32-half) reduces TWO
// nodes at once; x2 unroll = 4 nodes/iter with 2 independent chains. Validity via w=0
// select (uniform loop bounds -> no divergent exit around shfls; clamped addresses).
// Per node: DS ops 6 -> 2.5, VALU ~25 -> ~13, loads 8B -> 16B.
__global__ __launch_bounds__(256) void attn_onepass(const ushort_t* __restrict__ hfeat,
    const int* __restrict__ seg, const float* __restrict__ q_star,
    float* __restrict__ r_part, float* __restrict__ z_part)
{
  __shared__ float sred[4][264];
  int b = blockIdx.x >> 4, p = blockIdx.x & 15;
  int w = threadIdx.x >> 6, lane = threadIdx.x & 63;
  int hi = lane >> 5, l5 = lane & 31;
  int s0 = seg[b], s1 = seg[b+1], len = s1 - s0;
  int q0 = s0 + ((len * p) >> 4);
  int q1 = s0 + ((len * (p+1)) >> 4);

  float S[8] = {0.f,0.f,0.f,0.f,0.f,0.f,0.f,0.f};
  float Z = 0.f;

  if (q0 < q1){
    // q fragment: dims l5*8 .. +8 (fp32), duplicated across halves
    const float* qp = q_star + (size_t)b*512 + l5*8;
    float qf[8];
    #pragma unroll
    for (int k=0;k<8;k++) qf[k] = qp[k];

    auto loadp = [&](int nn)->short8{
      int nc = nn < q1 ? nn : (q1 - 1);
      return *(const short8*)(hfeat + (size_t)nc*256 + l5*8);
    };

    // wave w handles nodes {base+hi, base+8+hi} per iter, base strides 16 (4 waves x 4 nodes)
    int base0 = q0 + 2*w;
    short8 va = loadp(base0 + hi);
    short8 vb = loadp(base0 + 8 + hi);
    for (int base = base0; base < q1; base += 16){
      short8 vc = loadp(base + 16 + hi);
      short8 vd = loadp(base + 24 + hi);
      float fA[8], fB[8];
      float dA = 0.f, dB = 0.f;
      #pragma unroll
      for (int k=0;k<8;k++){
        fA[k] = bf2f((ushort_t)va[k]);
        fB[k] = bf2f((ushort_t)vb[k]);
        dA += fA[k]*qf[k];
        dB += fB[k]*qf[k];
      }
      #pragma unroll
      for (int off = 16; off; off >>= 1){
        dA += __shfl_xor(dA, off);
        dB += __shfl_xor(dB, off);
      }
      float wA = (base + hi     < q1) ? __expf(dA) : 0.f;
      float wB = (base + 8 + hi < q1) ? __expf(dB) : 0.f;
      Z += wA + wB;
      #pragma unroll
      for (int k=0;k<8;k++)
        S[k] += wA*fA[k] + wB*fB[k];
      va = vc; vb = vd;
    }
  }

  // cross-half merge: dims l5*8+k final = half-A sum + half-B sum
  #pragma unroll
  for (int k=0;k<8;k++) S[k] += __shfl_xor(S[k], 32);
  Z += __shfl_xor(Z, 32);

  if (hi == 0){
    *(float4*)&sred[w][l5*8]     = (float4){S[0],S[1],S[2],S[3]};
    *(float4*)&sred[w][l5*8 + 4] = (float4){S[4],S[5],S[6],S[7]};
    if (l5 == 0) sred[w][256] = Z;
  }
  __syncthreads();
  int f = threadIdx.x;
  {
    float v = sred[0][f] + sred[1][f] + sred[2][f] + sred[3][f];
    r_part[((size_t)p*128 + b)*256 + f] = v;
    if (f == 0)
      z_part[p*128 + b] = sred[0][256] + sred[1][256] + sred[2][256] + sred[3][256];
  }
}

// ================= finalize: r = sum(partials)/Z -> q_star/xc0; last: output GEMM =========
__global__ __launch_bounds__(256) void attn_fin(const float* __restrict__ r_part,
    const float* __restrict__ z_part, float* __restrict__ q_star, ushort_t* __restrict__ xc0,
    const float* __restrict__ outW, const float* __restrict__ outb,
    float* __restrict__ out, int last)
{
  __shared__ float qs[512];
  int b = blockIdx.x, f = threadIdx.x;
  float s = 0.f, z = 0.f;
  #pragma unroll
  for (int t = 0; t < 16; t++){
    s += r_part[((size_t)(t*128 + b))*256 + f];
    z += z_part[t*128 + b];
  }
  float v = s / (z + 1e-16f);
  q_star[b*512 + 256 + f] = v;
  xc0[b*768 + 256 + f] = f2bf(v);
  if (last){
    qs[f] = q_star[b*512 + f];     // q half (written by lstm2, prior dispatch)
    qs[256 + f] = v;               // r half (computed here)
    __syncthreads();
    if (f < 128){
      float acc = outb[f];
      for (int k = 0; k < 512; k++) acc += qs[k] * outW[k*128 + f];
      out[b*128 + f] = acc;
    }
  }
}

// ================= prep: fragment-major weight packing + all zero/init =================
// Packed layout per 16-col tile T, 32-k chunk kc: [(T*KC + kc)*64 + lane]*8 + j,
// where lane holds BT[n = T*16 + (lane&15)][k = kc*32 + (lane>>4)*8 + j].
__global__ void prep_all(const float* __restrict__ W1, const float* __restrict__ W2,
    const float* __restrict__ Wih0, const float* __restrict__ Whh0,
    const float* __restrict__ Wih1, const float* __restrict__ Whh1,
    const float* __restrict__ Wih2, const float* __restrict__ Whh2,
    const float* __restrict__ bih0, const float* __restrict__ bhh0,
    const float* __restrict__ bih1, const float* __restrict__ bhh1,
    const float* __restrict__ bih2, const float* __restrict__ bhh2,
    const int* __restrict__ bidx,
    ushort_t* __restrict__ W1P, ushort_t* __restrict__ W2P,
    ushort_t* __restrict__ Wc0P, ushort_t* __restrict__ Wc1P, ushort_t* __restrict__ Wc2P,
    float* __restrict__ c, ushort_t* __restrict__ xc, float* __restrict__ q_star,
    float* __restrict__ bc, int* __restrict__ seg)
{
  int i = blockIdx.x*256 + threadIdx.x;
  // --- W1P / W2P: K=256, KC=8, tile size 4096 ---
  if (i < 131072){
    const float* W = (i < 65536) ? W1 : W2;
    ushort_t* P = (i < 65536) ? W1P : W2P;
    int r = i & 65535;
    int T = r >> 12, r2 = r & 4095;
    int kc = r2 >> 9, l = (r2 >> 3) & 63, j = r2 & 7;
    int k = kc*32 + ((l>>4)<<3) + j;
    int n = T*16 + (l & 15);
    P[r] = f2bf(W[k*256 + n]);
    return;
  }
  i -= 131072;
  // --- Wc0P: K=768, KC=24, tile size 12288, 64 tiles ---
  if (i < 786432){
    int T = i / 12288, r2 = i - T*12288;
    int kc = r2 >> 9, l = (r2 >> 3) & 63, j = r2 & 7;
    int k = kc*32 + ((l>>4)<<3) + j;
    int g = T >> 4, n = (T & 15)*16 + (l & 15);
    int row = g*256 + n;
    Wc0P[i] = f2bf(k < 512 ? Wih0[row*512 + k] : Whh0[row*256 + (k - 512)]);
    return;
  }
  i -= 786432;
  // --- Wc1P / Wc2P: K=512, KC=16, tile size 8192, 64 tiles each ---
  if (i < 1048576){
    const float* Wih = (i < 524288) ? Wih1 : Wih2;
    const float* Whh = (i < 524288) ? Whh1 : Whh2;
    ushort_t* P = (i < 524288) ? Wc1P : Wc2P;
    int r = i & 524287;
    int T = r >> 13, r2 = r & 8191;
    int kc = r2 >> 9, l = (r2 >> 3) & 63, j = r2 & 7;
    int k = kc*32 + ((l>>4)<<3) + j;
    int g = T >> 4, n = (T & 15)*16 + (l & 15);
    int row = g*256 + n;
    P[r] = f2bf(k < 256 ? Wih[row*256 + k] : Whh[row*256 + (k - 256)]);
    return;
  }
  i -= 1048576;
  if (i < 98304) { c[i] = 0.f; return; }
  i -= 98304;
  if (i < 229376) { xc[i] = 0; return; }
  i -= 229376;
  if (i < 65536) { q_star[i] = 0.f; return; }
  i -= 65536;
  if (i < 3072) {
    int l = i >> 10, g = i & 1023;
    const float* bi = (l == 0) ? bih0 : ((l == 1) ? bih1 : bih2);
    const float* bh = (l == 0) ? bhh0 : ((l == 1) ? bhh1 : bhh2);
    bc[i] = bi[g] + bh[g];
    return;
  }
  i -= 3072;
  if (i < 129) {
    int lo = 0, hi = NN;
    while (lo < hi){ int mid = (lo + hi) >> 1; if (bidx[mid] < i) lo = mid + 1; else hi = mid; }
    seg[i] = lo;
    return;
  }
}

extern "C" void kernel_launch(void* const* d_in, const int* in_sizes, int n_in,
                              void* d_out, int out_size, void* d_ws, size_t ws_size,
                              hipStream_t stream)
{
  const float* x    = (const float*)d_in[0];
  const int*   bidx = (const int*)  d_in[1];
  const float* W1   = (const float*)d_in[2];
  const float* b1   = (const float*)d_in[3];
  const float* W2   = (const float*)d_in[4];
  const float* b2   = (const float*)d_in[5];
  const float* Wih0 = (const float*)d_in[6];
  const float* Whh0 = (const float*)d_in[7];
  const float* bih0 = (const float*)d_in[8];
  const float* bhh0 = (const float*)d_in[9];
  const float* Wih1 = (const float*)d_in[10];
  const float* Whh1 = (const float*)d_in[11];
  const float* bih1 = (const float*)d_in[12];
  const float* bhh1 = (const float*)d_in[13];
  const float* Wih2 = (const float*)d_in[14];
  const float* Whh2 = (const float*)d_in[15];
  const float* bih2 = (const float*)d_in[16];
  const float* bhh2 = (const float*)d_in[17];
  const float* outW = (const float*)d_in[18];
  const float* outb = (const float*)d_in[19];

  char* p = (char*)d_ws;
  auto alloc = [&](size_t bytes)->char*{ char* r = p; p += (bytes + 255) & ~(size_t)255; return r; };
  ushort_t* hfeat  = (ushort_t*)alloc((size_t)NN*256*2);   // bf16 node features
  ushort_t* W1P    = (ushort_t*)alloc(65536*2);
  ushort_t* W2P    = (ushort_t*)alloc(65536*2);
  ushort_t* Wc0P   = (ushort_t*)alloc(786432*2);
  ushort_t* Wc1P   = (ushort_t*)alloc(524288*2);
  ushort_t* Wc2P   = (ushort_t*)alloc(524288*2);
  float*    bc     = (float*)   alloc(3072*4);
  float*    c_all  = (float*)   alloc(98304*4);
  ushort_t* xc     = (ushort_t*)alloc(229376*2);           // xc0(128x768)|xc1(128x512)|xc2(128x512)
  float*    q_star = (float*)   alloc(65536*4);            // (128,512) fp32
  float*    r_part = (float*)   alloc((size_t)16*128*256*4); // per-sixteenth attention partials
  float*    z_part = (float*)   alloc(16*128*4);
  int*      seg    = (int*)     alloc(129*4);

  ushort_t* xc0 = xc;
  ushort_t* xc1 = xc + 98304;
  ushort_t* xc2 = xc + 163840;
  float* c0 = c_all, *c1 = c_all + 32768, *c2 = c_all + 65536;
  float* bc0 = bc, *bc1 = bc + 1024, *bc2 = bc + 2048;

  prep_all<<<9229, 256, 0, stream>>>(W1, W2, Wih0, Whh0, Wih1, Whh1, Wih2, Whh2,
                                     bih0, bhh0, bih1, bhh1, bih2, bhh2, bidx,
                                     W1P, W2P, Wc0P, Wc1P, Wc2P,
                                     c_all, xc, q_star, bc, seg);

  fnn_fused<<<3125, 512, 0, stream>>>(x, W1P, b1, W2P, b2, hfeat, NN);

  for (int s = 0; s < NSTEP; s++){
    // layer 0: in = [q | r | h0_prev] (K=768, KC=24)
    lstm_layer<<<128, 256, 0, stream>>>(xc0, 768, Wc0P, bc0, 24, c0, xc0 + 512, 768, xc1, 512, nullptr);
    // layer 1: in = [h0 | h1_prev] (K=512, KC=16)
    lstm_layer<<<128, 256, 0, stream>>>(xc1, 512, Wc1P, bc1, 16, c1, xc1 + 256, 512, xc2, 512, nullptr);
    // layer 2: in = [h1 | h2_prev] (K=512); h2 = q
    lstm_layer<<<128, 256, 0, stream>>>(xc2, 512, Wc2P, bc2, 16, c2, xc2 + 256, 512, xc0, 768, q_star);
    // segment-owned attention (16-way split, half-wave pairs) + finalize
    attn_onepass<<<2048, 256, 0, stream>>>(hfeat, seg, q_star, r_part, z_part);
    attn_fin<<<128, 256, 0, stream>>>(r_part, z_part, q_star, xc0, outW, outb,
                                      (float*)d_out, s == NSTEP-1 ? 1 : 0);
  }
}